// Round 4
// baseline (579.727 us; speedup 1.0000x reference)
//
#include <hip/hip_runtime.h>

#define HSZ 64
#define ISZ 8
#define TSZ 512
#define KP  168   // k per row: [0,64) h_hi | [64,72) x | [72,96) 0 | [96,160) h_lo | pad

typedef _Float16 f16;
typedef __attribute__((ext_vector_type(8))) _Float16 f16x8;
typedef __attribute__((ext_vector_type(4))) float f32x4;
typedef unsigned short u16;

__device__ __forceinline__ u16 f16bits(float f) {
    union { f16 h; u16 u; } v; v.h = (f16)f;
    return v.u;
}
__device__ __forceinline__ float sigm(float x) {
    return __builtin_amdgcn_rcpf(1.0f + __builtin_amdgcn_exp2f(-1.442695041f * x));
}
__device__ __forceinline__ float tanh_(float x) {
    return fmaf(2.0f, __builtin_amdgcn_rcpf(1.0f + __builtin_amdgcn_exp2f(-2.885390082f * x)), -1.0f);
}

struct Frags { f16x8 ah0, ah1, ax, al0, al1; };

__device__ __forceinline__ Frags read_frags(const u16* tbase, int lr, int lg) {
    const u16* rowp = tbase + lr * KP;
    Frags f;
    f.ah0 = *reinterpret_cast<const f16x8*>(rowp + lg * 8);
    f.ah1 = *reinterpret_cast<const f16x8*>(rowp + 32 + lg * 8);
    f.ax  = *reinterpret_cast<const f16x8*>(rowp + 64 + lg * 8);
    f.al0 = *reinterpret_cast<const f16x8*>(rowp + 96 + lg * 8);
    f.al1 = *reinterpret_cast<const f16x8*>(rowp + 128 + lg * 8);
    return f;
}

__device__ __forceinline__ void do_mfma(const Frags& f,
    const f16x8 (&bh)[4][2], const f16x8 (&bx)[4], const float (&bias)[4],
    f32x4 (&acc)[4])
{
#pragma unroll
    for (int g = 0; g < 4; ++g) acc[g] = f32x4{bias[g], bias[g], bias[g], bias[g]};
#pragma unroll
    for (int g = 0; g < 4; ++g) {
        acc[g] = __builtin_amdgcn_mfma_f32_16x16x32_f16(f.ah0, bh[g][0], acc[g], 0, 0, 0);
        acc[g] = __builtin_amdgcn_mfma_f32_16x16x32_f16(f.ah1, bh[g][1], acc[g], 0, 0, 0);
        acc[g] = __builtin_amdgcn_mfma_f32_16x16x32_f16(f.ax,  bx[g],    acc[g], 0, 0, 0);
        acc[g] = __builtin_amdgcn_mfma_f32_16x16x32_f16(f.al0, bh[g][0], acc[g], 0, 0, 0);
        acc[g] = __builtin_amdgcn_mfma_f32_16x16x32_f16(f.al1, bh[g][1], acc[g], 0, 0, 0);
    }
}

// Redistribute the 8 valid rows (lanes lg<2) so all 64 lanes activate 2 units
// full-exec, then LSTM cell update + write h (hi+lo f16) back to the group tile.
__device__ __forceinline__ void act_update(
    const f32x4 (&acc)[4], float (&c)[2], float (&hv)[2],
    u16* tbase, int row0, int col, bool lo32)
{
    float p0[4], p1[4];
#pragma unroll
    for (int g = 0; g < 4; ++g) {
        const float s2 = __shfl_xor(acc[g][2], 32);
        const float s3 = __shfl_xor(acc[g][3], 32);
        p0[g] = lo32 ? acc[g][0] : s2;
        p1[g] = lo32 ? acc[g][1] : s3;
    }
#pragma unroll
    for (int u = 0; u < 2; ++u) {
        const float* p = u ? p1 : p0;
        const float ig = sigm(p[0]);
        const float fg = sigm(p[1]);
        const float gg = tanh_(p[2]);
        const float og = sigm(p[3]);
        c[u]  = fmaf(fg, c[u], ig * gg);
        hv[u] = og * tanh_(c[u]);
        const f16 hi = (f16)hv[u];
        const f16 lo = (f16)(hv[u] - (float)hi);
        union { f16 h; u16 b; } vh, vl; vh.h = hi; vl.h = lo;
        u16* rp = tbase + (row0 + u) * KP;
        rp[col]      = vh.b;
        rp[96 + col] = vl.b;
    }
}

// 4 waves per block, 16 batch rows split into two skewed groups of 8.
// SegA: MFMA(G0,t) overlapped with act(G1,t-1). SegB: MFMA(G1,t) with act(G0,t).
__global__ __launch_bounds__(256) void lstm_skew(
    const float* __restrict__ x,      // [B, T, I]
    const float* __restrict__ W_ih,   // [4H, I]
    const float* __restrict__ W_hh,   // [4H, H]
    const float* __restrict__ b_ih,   // [4H]
    const float* __restrict__ b_hh,   // [4H]
    const float* __restrict__ W_fc,   // [O, H]
    const float* __restrict__ b_fc,   // [O]
    float* __restrict__ out)          // [B, O]
{
    const int tid = threadIdx.x;
    const int w  = tid >> 6;
    const int l  = tid & 63;
    const int lr = l & 15;
    const int lg = l >> 4;
    const int B0 = blockIdx.x * 16;
    const bool lo32 = (l < 32);
    // unit rows after redistribution: lanes<32 keep elems 0,1; lanes>=32 get
    // (lane-32)'s elems 2,3.  lg 0,1,2,3 -> rows {0,1},{4,5},{2,3},{6,7}
    const int row0 = lo32 ? lg * 4 : (lg - 2) * 4 + 2;
    const int col  = w * 16 + lr;

    __shared__ __align__(16) u16 tile[2][16][KP];  // [group][row][k]
    __shared__ float red[4][16];

    for (int i = tid; i < 2 * 16 * KP; i += 256)
        ((u16*)tile)[i] = 0;

    // ---- weights (single f16) + bias into registers ----
    f16x8 bh[4][2], bx[4];
    float bias[4];
#pragma unroll
    for (int g = 0; g < 4; ++g) {
        const int row = g * HSZ + w * 16 + lr;
#pragma unroll
        for (int kt = 0; kt < 2; ++kt) {
            const float4 a = *reinterpret_cast<const float4*>(&W_hh[row * HSZ + kt * 32 + lg * 8]);
            const float4 b = *reinterpret_cast<const float4*>(&W_hh[row * HSZ + kt * 32 + lg * 8 + 4]);
            bh[g][kt][0] = (f16)a.x; bh[g][kt][1] = (f16)a.y;
            bh[g][kt][2] = (f16)a.z; bh[g][kt][3] = (f16)a.w;
            bh[g][kt][4] = (f16)b.x; bh[g][kt][5] = (f16)b.y;
            bh[g][kt][6] = (f16)b.z; bh[g][kt][7] = (f16)b.w;
        }
        if (lg == 0) {
            const float4 a = *reinterpret_cast<const float4*>(&W_ih[row * ISZ]);
            const float4 b = *reinterpret_cast<const float4*>(&W_ih[row * ISZ + 4]);
            bx[g][0] = (f16)a.x; bx[g][1] = (f16)a.y;
            bx[g][2] = (f16)a.z; bx[g][3] = (f16)a.w;
            bx[g][4] = (f16)b.x; bx[g][5] = (f16)b.y;
            bx[g][6] = (f16)b.z; bx[g][7] = (f16)b.w;
        } else {
#pragma unroll
            for (int j = 0; j < 8; ++j) bx[g][j] = (f16)0.0f;
        }
        bias[g] = b_ih[row] + b_hh[row];
    }

    __syncthreads();  // zeroing done

    // stage x(0) for G0 (G1's x(0) is staged inside SegA(0))
    if (tid < 64) {
        const int row = tid >> 3, i = tid & 7;
        tile[0][row][64 + i] = f16bits(x[((size_t)(B0 + row) * TSZ + 0) * ISZ + i]);
    }
    __syncthreads();

    float cG0[2] = {0.f, 0.f}, cG1[2] = {0.f, 0.f};
    float hvG0[2] = {0.f, 0.f}, hvG1[2] = {0.f, 0.f};
    f32x4 accA[4], accB[4];

    const int xrow = l >> 3, xi = l & 7;

    for (int t = 0; t < TSZ; ++t) {
        // ===== Segment A: MFMA G0(t); act G1(t-1); stage x_G1(t) =====
        float xg1 = 0.f;
        if (w == 3)
            xg1 = x[((size_t)(B0 + 8 + xrow) * TSZ + t) * ISZ + xi];
        const Frags fa = read_frags(&tile[0][0][0], lr, lg);
        if (t > 0)
            act_update(accB, cG1, hvG1, &tile[1][0][0], row0, col, lo32);
        do_mfma(fa, bh, bx, bias, accA);
        if (w == 3)
            tile[1][xrow][64 + xi] = f16bits(xg1);
        __syncthreads();

        // ===== Segment B: MFMA G1(t); act G0(t); stage x_G0(t+1) =====
        float xg0 = 0.f;
        if (w == 3 && t + 1 < TSZ)
            xg0 = x[((size_t)(B0 + xrow) * TSZ + (t + 1)) * ISZ + xi];
        const Frags fb = read_frags(&tile[1][0][0], lr, lg);
        act_update(accA, cG0, hvG0, &tile[0][0][0], row0, col, lo32);
        do_mfma(fb, bh, bx, bias, accB);
        if (w == 3 && t + 1 < TSZ)
            tile[0][xrow][64 + xi] = f16bits(xg0);
        __syncthreads();
    }

    // drain: act G1(511)
    act_update(accB, cG1, hvG1, &tile[1][0][0], row0, col, lo32);

    // ---- final FC ----
    const float wfc = W_fc[col];
    float v00 = hvG0[0] * wfc, v01 = hvG0[1] * wfc;
    float v10 = hvG1[0] * wfc, v11 = hvG1[1] * wfc;
#pragma unroll
    for (int off = 1; off < 16; off <<= 1) {
        v00 += __shfl_xor(v00, off);
        v01 += __shfl_xor(v01, off);
        v10 += __shfl_xor(v10, off);
        v11 += __shfl_xor(v11, off);
    }
    if (lr == 0) {
        red[w][row0]         = v00;
        red[w][row0 + 1]     = v01;
        red[w][8 + row0]     = v10;
        red[w][8 + row0 + 1] = v11;
    }
    __syncthreads();
    if (tid < 16)
        out[B0 + tid] = red[0][tid] + red[1][tid] + red[2][tid] + red[3][tid] + b_fc[0];
}

extern "C" void kernel_launch(void* const* d_in, const int* in_sizes, int n_in,
                              void* d_out, int out_size, void* d_ws, size_t ws_size,
                              hipStream_t stream) {
    const float* x    = (const float*)d_in[0];
    const float* W_ih = (const float*)d_in[1];
    const float* W_hh = (const float*)d_in[2];
    const float* b_ih = (const float*)d_in[3];
    const float* b_hh = (const float*)d_in[4];
    const float* W_fc = (const float*)d_in[5];
    const float* b_fc = (const float*)d_in[6];
    float* out = (float*)d_out;

    const int B = in_sizes[0] / (TSZ * ISZ);  // 4096
    lstm_skew<<<B / 16, 256, 0, stream>>>(x, W_ih, W_hh, b_ih, b_hh, W_fc, b_fc, out);
}

// Round 5
// 336.720 us; speedup vs baseline: 1.7217x; 1.7217x over previous
//
#include <hip/hip_runtime.h>

#define HSZ 64
#define ISZ 8
#define TSZ 512
#define BTILE 8    // batch rows per block (8 valid rows in a 16-row MFMA tile)
#define KP  104    // k per row: [0,64) h | [64,72) x | [72,96) zero | pad; 208 B stride

typedef _Float16 f16;
typedef __attribute__((ext_vector_type(8))) _Float16 f16x8;
typedef __attribute__((ext_vector_type(4))) float f32x4;
typedef unsigned short u16;

__device__ __forceinline__ u16 f16bits(float f) {
    union { f16 h; u16 u; } v; v.h = (f16)f;
    return v.u;
}
__device__ __forceinline__ float sigm(float x) {
    return __builtin_amdgcn_rcpf(1.0f + __builtin_amdgcn_exp2f(-1.442695041f * x));
}
__device__ __forceinline__ float tanh_(float x) {
    return fmaf(2.0f, __builtin_amdgcn_rcpf(1.0f + __builtin_amdgcn_exp2f(-2.885390082f * x)), -1.0f);
}

// 4 waves/block, 8 batch rows/block -> 512 blocks = 2 blocks/CU (TLP).
// Wave w owns hidden cols [16w,16w+16) for all 4 gates. 3 MFMA per gate-step:
// h (single f16) k[0,64) + x k[64,72). h write-back f32->f16, c stays f32 in regs.
__global__ __launch_bounds__(256) void lstm_b8(
    const float* __restrict__ x,      // [B, T, I]
    const float* __restrict__ W_ih,   // [4H, I]
    const float* __restrict__ W_hh,   // [4H, H]
    const float* __restrict__ b_ih,   // [4H]
    const float* __restrict__ b_hh,   // [4H]
    const float* __restrict__ W_fc,   // [O, H]
    const float* __restrict__ b_fc,   // [O]
    float* __restrict__ out)          // [B, O]
{
    const int tid = threadIdx.x;
    const int w  = tid >> 6;
    const int l  = tid & 63;
    const int lr = l & 15;
    const int lg = l >> 4;
    const int B0 = blockIdx.x * BTILE;
    const bool lo32 = (l < 32);
    // after xor32 redistribution, this lane activates rows {row0, row0+1}:
    // lo32 keeps acc elems 0,1 (rows lg*4+{0,1}); hi32 takes partner's elems 2,3
    const int row0 = lo32 ? lg * 4 : (lg - 2) * 4 + 2;
    const int col  = w * 16 + lr;

    __shared__ __align__(16) u16 tile[2][16][KP];  // [buf][row][k]; rows 8-15 stay 0
    __shared__ float red[4][BTILE];

    for (int i = tid; i < 2 * 16 * KP; i += 256)
        ((u16*)tile)[i] = 0;

    // ---- weights (single f16) + bias into registers ----
    f16x8 bh[4][2], bx[4];
    float bias[4];
#pragma unroll
    for (int g = 0; g < 4; ++g) {
        const int row = g * HSZ + w * 16 + lr;
#pragma unroll
        for (int kt = 0; kt < 2; ++kt) {
            const float4 a = *reinterpret_cast<const float4*>(&W_hh[row * HSZ + kt * 32 + lg * 8]);
            const float4 b = *reinterpret_cast<const float4*>(&W_hh[row * HSZ + kt * 32 + lg * 8 + 4]);
            bh[g][kt][0] = (f16)a.x; bh[g][kt][1] = (f16)a.y;
            bh[g][kt][2] = (f16)a.z; bh[g][kt][3] = (f16)a.w;
            bh[g][kt][4] = (f16)b.x; bh[g][kt][5] = (f16)b.y;
            bh[g][kt][6] = (f16)b.z; bh[g][kt][7] = (f16)b.w;
        }
        if (lg == 0) {
            const float4 a = *reinterpret_cast<const float4*>(&W_ih[row * ISZ]);
            const float4 b = *reinterpret_cast<const float4*>(&W_ih[row * ISZ + 4]);
            bx[g][0] = (f16)a.x; bx[g][1] = (f16)a.y;
            bx[g][2] = (f16)a.z; bx[g][3] = (f16)a.w;
            bx[g][4] = (f16)b.x; bx[g][5] = (f16)b.y;
            bx[g][6] = (f16)b.z; bx[g][7] = (f16)b.w;
        } else {
#pragma unroll
            for (int j = 0; j < 8; ++j) bx[g][j] = (f16)0.0f;
        }
        bias[g] = b_ih[row] + b_hh[row];
    }

    __syncthreads();  // zeroing visible

    // stage x(0): 8 rows x 8 inputs by the first 64 threads
    if (tid < 64) {
        const int rb = tid >> 3, ip = tid & 7;
        tile[0][rb][HSZ + ip] = f16bits(x[((size_t)(B0 + rb) * TSZ + 0) * ISZ + ip]);
    }
    __syncthreads();

    float c2[2]  = {0.f, 0.f};
    float hv2[2] = {0.f, 0.f};
    const int rb = l >> 3, ip = l & 7;

    for (int t = 0; t < TSZ; ++t) {
        const int buf = t & 1, bufn = buf ^ 1;

        // prefetch x(t+1) (hidden under MFMA + act)
        float xv = 0.f;
        if (w == 0 && t + 1 < TSZ)
            xv = x[((size_t)(B0 + rb) * TSZ + (t + 1)) * ISZ + ip];

        // A fragments: row lr, 3 x 16B
        const u16* rowp = &tile[buf][lr][0];
        const f16x8 a0 = *reinterpret_cast<const f16x8*>(rowp + lg * 8);
        const f16x8 a1 = *reinterpret_cast<const f16x8*>(rowp + 32 + lg * 8);
        const f16x8 ax = *reinterpret_cast<const f16x8*>(rowp + 64 + lg * 8);

        f32x4 acc[4];
#pragma unroll
        for (int g = 0; g < 4; ++g) acc[g] = f32x4{bias[g], bias[g], bias[g], bias[g]};
#pragma unroll
        for (int g = 0; g < 4; ++g) {
            acc[g] = __builtin_amdgcn_mfma_f32_16x16x32_f16(a0, bh[g][0], acc[g], 0, 0, 0);
            acc[g] = __builtin_amdgcn_mfma_f32_16x16x32_f16(a1, bh[g][1], acc[g], 0, 0, 0);
            acc[g] = __builtin_amdgcn_mfma_f32_16x16x32_f16(ax, bx[g],    acc[g], 0, 0, 0);
        }

        // redistribute 8 valid rows across all 64 lanes (2 units/lane, full exec)
        float p0[4], p1[4];
#pragma unroll
        for (int g = 0; g < 4; ++g) {
            const float s2 = __shfl_xor(acc[g][2], 32);
            const float s3 = __shfl_xor(acc[g][3], 32);
            p0[g] = lo32 ? acc[g][0] : s2;
            p1[g] = lo32 ? acc[g][1] : s3;
        }
#pragma unroll
        for (int u = 0; u < 2; ++u) {
            const float* p = u ? p1 : p0;
            const float ig = sigm(p[0]);
            const float fg = sigm(p[1]);
            const float gg = tanh_(p[2]);
            const float og = sigm(p[3]);
            c2[u]  = fmaf(fg, c2[u], ig * gg);
            hv2[u] = og * tanh_(c2[u]);
            tile[bufn][row0 + u][col] = f16bits(hv2[u]);
        }

        if (w == 0 && t + 1 < TSZ)
            tile[bufn][rb][HSZ + ip] = f16bits(xv);
        __syncthreads();
    }

    // ---- final FC: out[b] = sum_hidden h * W_fc + b_fc ----
    const float wfc = W_fc[col];
    float v0 = hv2[0] * wfc, v1 = hv2[1] * wfc;
#pragma unroll
    for (int off = 1; off < 16; off <<= 1) {
        v0 += __shfl_xor(v0, off);
        v1 += __shfl_xor(v1, off);
    }
    if (lr == 0) {
        red[w][row0]     = v0;
        red[w][row0 + 1] = v1;
    }
    __syncthreads();
    if (tid < BTILE)
        out[B0 + tid] = red[0][tid] + red[1][tid] + red[2][tid] + red[3][tid] + b_fc[0];
}

extern "C" void kernel_launch(void* const* d_in, const int* in_sizes, int n_in,
                              void* d_out, int out_size, void* d_ws, size_t ws_size,
                              hipStream_t stream) {
    const float* x    = (const float*)d_in[0];
    const float* W_ih = (const float*)d_in[1];
    const float* W_hh = (const float*)d_in[2];
    const float* b_ih = (const float*)d_in[3];
    const float* b_hh = (const float*)d_in[4];
    const float* W_fc = (const float*)d_in[5];
    const float* b_fc = (const float*)d_in[6];
    float* out = (float*)d_out;

    const int B = in_sizes[0] / (TSZ * ISZ);  // 4096
    lstm_b8<<<B / BTILE, 256, 0, stream>>>(x, W_ih, W_hh, b_ih, b_hh, W_fc, b_fc, out);
}

// Round 6
// 316.835 us; speedup vs baseline: 1.8297x; 1.0628x over previous
//
#include <hip/hip_runtime.h>

#define HSZ 64
#define ISZ 8
#define TSZ 512
#define BTILE 8    // batch rows per block (8 valid rows in a 16-row MFMA tile)
#define KP  104    // k per row: [0,64) h | [64,72) x | [72,96) zero | pad; 208 B stride

typedef _Float16 f16;
typedef __attribute__((ext_vector_type(8))) _Float16 f16x8;
typedef __attribute__((ext_vector_type(4))) float f32x4;
typedef unsigned short u16;

__device__ __forceinline__ u16 f16bits(float f) {
    union { f16 h; u16 u; } v; v.h = (f16)f;
    return v.u;
}

// 4 waves/block, 8 batch rows/block -> 512 blocks = 2 blocks/CU (TLP).
// Wave w owns hidden cols [16w,16w+16) for all 4 gates. 3 MFMA per gate-step.
// Cell update uses common-denominator algebra: 5 exp2 + 2 rcp per unit
// (was 5 exp2 + 5 rcp) to cut transcendental issue, the measured wall.
__global__ __launch_bounds__(256) void lstm_b8t(
    const float* __restrict__ x,      // [B, T, I]
    const float* __restrict__ W_ih,   // [4H, I]
    const float* __restrict__ W_hh,   // [4H, H]
    const float* __restrict__ b_ih,   // [4H]
    const float* __restrict__ b_hh,   // [4H]
    const float* __restrict__ W_fc,   // [O, H]
    const float* __restrict__ b_fc,   // [O]
    float* __restrict__ out)          // [B, O]
{
    const int tid = threadIdx.x;
    const int w  = tid >> 6;
    const int l  = tid & 63;
    const int lr = l & 15;
    const int lg = l >> 4;
    const int B0 = blockIdx.x * BTILE;
    const bool lo32 = (l < 32);
    // after xor32 redistribution, this lane activates rows {row0, row0+1}
    const int row0 = lo32 ? lg * 4 : (lg - 2) * 4 + 2;
    const int col  = w * 16 + lr;

    __shared__ __align__(16) u16 tile[2][16][KP];  // [buf][row][k]; rows 8-15 stay 0
    __shared__ float red[4][BTILE];

    for (int i = tid; i < 2 * 16 * KP; i += 256)
        ((u16*)tile)[i] = 0;

    // ---- weights (single f16) + bias into registers ----
    f16x8 bh[4][2], bx[4];
    float bias[4];
#pragma unroll
    for (int g = 0; g < 4; ++g) {
        const int row = g * HSZ + w * 16 + lr;
#pragma unroll
        for (int kt = 0; kt < 2; ++kt) {
            const float4 a = *reinterpret_cast<const float4*>(&W_hh[row * HSZ + kt * 32 + lg * 8]);
            const float4 b = *reinterpret_cast<const float4*>(&W_hh[row * HSZ + kt * 32 + lg * 8 + 4]);
            bh[g][kt][0] = (f16)a.x; bh[g][kt][1] = (f16)a.y;
            bh[g][kt][2] = (f16)a.z; bh[g][kt][3] = (f16)a.w;
            bh[g][kt][4] = (f16)b.x; bh[g][kt][5] = (f16)b.y;
            bh[g][kt][6] = (f16)b.z; bh[g][kt][7] = (f16)b.w;
        }
        if (lg == 0) {
            const float4 a = *reinterpret_cast<const float4*>(&W_ih[row * ISZ]);
            const float4 b = *reinterpret_cast<const float4*>(&W_ih[row * ISZ + 4]);
            bx[g][0] = (f16)a.x; bx[g][1] = (f16)a.y;
            bx[g][2] = (f16)a.z; bx[g][3] = (f16)a.w;
            bx[g][4] = (f16)b.x; bx[g][5] = (f16)b.y;
            bx[g][6] = (f16)b.z; bx[g][7] = (f16)b.w;
        } else {
#pragma unroll
            for (int j = 0; j < 8; ++j) bx[g][j] = (f16)0.0f;
        }
        bias[g] = b_ih[row] + b_hh[row];
    }

    __syncthreads();  // zeroing visible

    // stage x(0): 8 rows x 8 inputs by the first 64 threads
    if (tid < 64) {
        const int rb0 = tid >> 3, ip0 = tid & 7;
        tile[0][rb0][HSZ + ip0] = f16bits(x[((size_t)(B0 + rb0) * TSZ + 0) * ISZ + ip0]);
    }
    __syncthreads();

    float c2[2]  = {0.f, 0.f};
    float hv2[2] = {0.f, 0.f};
    const int rb = l >> 3, ip = l & 7;
    const float L1 = 1.442695041f;   // log2(e)
    const float L2 = 2.885390082f;   // 2*log2(e)

    for (int t = 0; t < TSZ; ++t) {
        const int buf = t & 1, bufn = buf ^ 1;

        // prefetch x(t+1) (hidden under MFMA + act)
        float xv = 0.f;
        if (w == 0 && t + 1 < TSZ)
            xv = x[((size_t)(B0 + rb) * TSZ + (t + 1)) * ISZ + ip];

        // A fragments: row lr, 3 x 16B
        const u16* rowp = &tile[buf][lr][0];
        const f16x8 a0 = *reinterpret_cast<const f16x8*>(rowp + lg * 8);
        const f16x8 a1 = *reinterpret_cast<const f16x8*>(rowp + 32 + lg * 8);
        const f16x8 ax = *reinterpret_cast<const f16x8*>(rowp + 64 + lg * 8);

        f32x4 acc[4];
#pragma unroll
        for (int g = 0; g < 4; ++g) acc[g] = f32x4{bias[g], bias[g], bias[g], bias[g]};
        __builtin_amdgcn_s_setprio(1);
#pragma unroll
        for (int g = 0; g < 4; ++g) {
            acc[g] = __builtin_amdgcn_mfma_f32_16x16x32_f16(a0, bh[g][0], acc[g], 0, 0, 0);
            acc[g] = __builtin_amdgcn_mfma_f32_16x16x32_f16(a1, bh[g][1], acc[g], 0, 0, 0);
            acc[g] = __builtin_amdgcn_mfma_f32_16x16x32_f16(ax, bx[g],    acc[g], 0, 0, 0);
        }
        __builtin_amdgcn_s_setprio(0);

        // redistribute 8 valid rows across all 64 lanes (2 units/lane, full exec)
        float p0[4], p1[4];
#pragma unroll
        for (int g = 0; g < 4; ++g) {
            const float s2 = __shfl_xor(acc[g][2], 32);
            const float s3 = __shfl_xor(acc[g][3], 32);
            p0[g] = lo32 ? acc[g][0] : s2;
            p1[g] = lo32 ? acc[g][1] : s3;
        }

        // cell update, common-denominator form: 5 exp2 + 2 rcp per unit.
        // i=1/(1+ea), f=1/(1+eb), g=(1-ed)/(1+ed), o=1/(1+es), tanh(c)=(1-eu)/(1+eu)
        // c' = [c*(1+ea)(1+ed) + (1-ed)(1+eb)] / [(1+ea)(1+eb)(1+ed)]
        // h  = (1-eu) / [(1+es)(1+eu)]
#pragma unroll
        for (int u = 0; u < 2; ++u) {
            const float* p = u ? p1 : p0;
            const float ea = __builtin_amdgcn_exp2f(-L1 * p[0]);
            const float eb = __builtin_amdgcn_exp2f(-L1 * p[1]);
            const float ed = __builtin_amdgcn_exp2f(-L2 * p[2]);
            const float es = __builtin_amdgcn_exp2f(-L1 * p[3]);
            const float A1 = 1.0f + ea, B1 = 1.0f + eb, D1 = 1.0f + ed;
            const float R1 = __builtin_amdgcn_rcpf(A1 * B1 * D1);
            const float num = fmaf(c2[u] * A1, D1, (1.0f - ed) * B1);
            c2[u] = num * R1;
            const float eu = __builtin_amdgcn_exp2f(-L2 * c2[u]);
            const float R2 = __builtin_amdgcn_rcpf((1.0f + es) * (1.0f + eu));
            hv2[u] = (1.0f - eu) * R2;
            tile[bufn][row0 + u][col] = f16bits(hv2[u]);
        }

        if (w == 0 && t + 1 < TSZ)
            tile[bufn][rb][HSZ + ip] = f16bits(xv);
        __syncthreads();
    }

    // ---- final FC: out[b] = sum_hidden h * W_fc + b_fc ----
    const float wfc = W_fc[col];
    float v0 = hv2[0] * wfc, v1 = hv2[1] * wfc;
#pragma unroll
    for (int off = 1; off < 16; off <<= 1) {
        v0 += __shfl_xor(v0, off);
        v1 += __shfl_xor(v1, off);
    }
    if (lr == 0) {
        red[w][row0]     = v0;
        red[w][row0 + 1] = v1;
    }
    __syncthreads();
    if (tid < BTILE)
        out[B0 + tid] = red[0][tid] + red[1][tid] + red[2][tid] + red[3][tid] + b_fc[0];
}

extern "C" void kernel_launch(void* const* d_in, const int* in_sizes, int n_in,
                              void* d_out, int out_size, void* d_ws, size_t ws_size,
                              hipStream_t stream) {
    const float* x    = (const float*)d_in[0];
    const float* W_ih = (const float*)d_in[1];
    const float* W_hh = (const float*)d_in[2];
    const float* b_ih = (const float*)d_in[3];
    const float* b_hh = (const float*)d_in[4];
    const float* W_fc = (const float*)d_in[5];
    const float* b_fc = (const float*)d_in[6];
    float* out = (float*)d_out;

    const int B = in_sizes[0] / (TSZ * ISZ);  // 4096
    lstm_b8t<<<B / BTILE, 256, 0, stream>>>(x, W_ih, W_hh, b_ih, b_hh, W_fc, b_fc, out);
}